// Round 5
// baseline (548.425 us; speedup 1.0000x reference)
//
#include <hip/hip_runtime.h>
#include <hip/hip_bf16.h>
#include <cstdint>
#include <cstddef>

// ---------------------------------------------------------------------------
// SelfAttention (B=2, S=4096, H=2048, fp32 in/out), fp16 MFMA internally.
// Round 5: 256x256 tile, 8 waves, BK=64, double-buffered LDS — ONE barrier +
// ONE vmcnt(0) per K-tile (vs round 3's 8 barriers per 2 tiles):
//   per tile: [24 C++ ds_reads of all frags] [STAGE8 next tile via
//   global_load_lds] [64 MFMA, setprio-wrapped] [vmcnt(0); s_barrier].
//   Compiler-managed counted lgkmcnt interleaves read-drains among MFMAs
//   (no inline-asm ds_read => no regalloc-copy hazard, rule #18 class).
// Race derivation: reads of buf b drain before tile-end barrier (consuming
// MFMAs precede it); STAGE8 writes b^1 whose readers drained before the
// PREVIOUS barrier (WAR); vmcnt(0)+barrier fences staged data (RAW).
// LDS swizzle: XOR (row&7)<<4 on read column; staging pre-swizzles the
// global source column (involution, both-sides rule) — verified rounds 2-3.
// ---------------------------------------------------------------------------

typedef _Float16 half8 __attribute__((ext_vector_type(8)));
typedef _Float16 half4 __attribute__((ext_vector_type(4)));
typedef float    f32x4 __attribute__((ext_vector_type(4)));

__device__ __forceinline__ void gld_lds16(const void* g, void* l) {
  __builtin_amdgcn_global_load_lds(
      (const __attribute__((address_space(1))) unsigned int*)g,
      (__attribute__((address_space(3))) unsigned int*)l, 16, 0, 0);
}

#define FENCE()  asm volatile("" ::: "memory")
#define VMC(n)   asm volatile("s_waitcnt vmcnt(" #n ")" ::: "memory")
#define SBARF()  do { __builtin_amdgcn_s_barrier(); FENCE(); } while (0)
#define PRIO1()  __builtin_amdgcn_s_setprio(1)
#define PRIO0()  __builtin_amdgcn_s_setprio(0)

// A subtile (m-half MH) from buffer RB: 4 m-frags x 2 k-slices, C++ reads
#define LOAD_A(dst, RB, MH) do {                                            \
  const char* _p = ldsA + ((RB)*2 + wr) * 16384 + fr * 128;                 \
  _Pragma("unroll") for (int mi = 0; mi < 4; ++mi) {                        \
    dst[mi][0] = *(const half8*)(_p + ((MH)*4 + mi) * 2048 + cS0);          \
    dst[mi][1] = *(const half8*)(_p + ((MH)*4 + mi) * 2048 + cS1);          \
  }                                                                         \
} while (0)

// B subtile (n-half NH) from buffer RB: 2 n-frags x 2 k-slices
#define LOAD_B(dst, RB, NH) do {                                            \
  const char* _p = ldsB + ((RB)*2 + (wc >> 1)) * 16384 +                    \
                   ((wc & 1) * 64 + fr) * 128;                              \
  _Pragma("unroll") for (int ni = 0; ni < 2; ++ni) {                        \
    dst[ni][0] = *(const half8*)(_p + ((NH)*2 + ni) * 2048 + cS0);          \
    dst[ni][1] = *(const half8*)(_p + ((NH)*2 + ni) * 2048 + cS1);          \
  }                                                                         \
} while (0)

// one C-quadrant x K=64: 16 MFMA
#define MFMA_Q(AF, BF, MH, NH)                                              \
  _Pragma("unroll") for (int mi = 0; mi < 4; ++mi)                          \
  _Pragma("unroll") for (int ni = 0; ni < 2; ++ni) {                        \
    f32x4& _c = acc[(MH)*4 + mi][(NH)*2 + ni];                              \
    _c = __builtin_amdgcn_mfma_f32_16x16x32_f16(AF[mi][0], BF[ni][0], _c, 0, 0, 0); \
    _c = __builtin_amdgcn_mfma_f32_16x16x32_f16(AF[mi][1], BF[ni][1], _c, 0, 0, 0); \
  }

// stage full K-tile (A+B, both 128-row halves) into buf BSEL: 8 gld_lds/wave
#define STAGE8(BSEL, KO) do {                                               \
  const size_t _k = (KO);                                                   \
  gld_lds16(Asrc + _k,               ldsc + (BSEL)*32768 + wvd);            \
  gld_lds16(Asrc + _k + lda8,        ldsc + (BSEL)*32768 + wvd + 1024);     \
  gld_lds16(Asrc + _k + ldaH,        ldsc + (BSEL)*32768 + 16384 + wvd);    \
  gld_lds16(Asrc + _k + ldaH + lda8, ldsc + (BSEL)*32768 + 16384 + wvd + 1024); \
  gld_lds16(Bsrc + _k,               ldsc + 65536 + (BSEL)*32768 + wvd);    \
  gld_lds16(Bsrc + _k + ldb8,        ldsc + 65536 + (BSEL)*32768 + wvd + 1024); \
  gld_lds16(Bsrc + _k + ldbH,        ldsc + 65536 + (BSEL)*32768 + 16384 + wvd); \
  gld_lds16(Bsrc + _k + ldbH + ldb8, ldsc + 65536 + (BSEL)*32768 + 16384 + wvd + 1024); \
} while (0)

// one K-tile: reads + next-tile stage + 64 MFMA + single fence pair
#define TILEB(RB, KO, DO_STAGE) do {                                        \
  LOAD_A(af0, RB, 0);                                                       \
  LOAD_B(b0,  RB, 0);                                                       \
  if (DO_STAGE) STAGE8((RB)^1, KO);                                         \
  LOAD_B(b1,  RB, 1);                                                       \
  LOAD_A(af1, RB, 1);                                                       \
  PRIO1();                                                                  \
  MFMA_Q(af0, b0, 0, 0);                                                    \
  MFMA_Q(af0, b1, 0, 1);                                                    \
  MFMA_Q(af1, b1, 1, 1);                                                    \
  MFMA_Q(af1, b0, 1, 0);                                                    \
  PRIO0();                                                                  \
  VMC(0);                                                                   \
  SBARF();                                                                  \
} while (0)

// MODE 0: fp32 row-major out, no bias   (scores, final out)
// MODE 1: fp16 row-major out + bias     (Q, K projections)
// MODE 2: fp16 TRANSPOSED out + bias    (V projection -> Vt[col*ldo + row])
template <int MODE>
__global__ __launch_bounds__(512, 2) void gemm256(
    const _Float16* __restrict__ A, int lda,
    const _Float16* __restrict__ B, int ldb,
    const float* __restrict__ bias,
    void* __restrict__ out, int ldo, int K,
    size_t sA, size_t sB, size_t sO)
{
  __shared__ __attribute__((aligned(128))) char lds[131072];
  char* ldsc = (char*)lds;
  char* ldsA = ldsc;             // per buf: A at +BSEL*32768, halves +0/+16384
  char* ldsB = ldsc + 65536;

  const int tid  = threadIdx.x;
  const int wv   = tid >> 6;
  const int lane = tid & 63;
  const int wr = wv >> 2;           // wave row (M half, 128 rows)
  const int wc = wv & 3;            // wave col (64 cols)
  const int bm = blockIdx.x * 256;
  const int bn = blockIdx.y * 256;
  A += (size_t)blockIdx.z * sA;
  B += (size_t)blockIdx.z * sB;

  // fragment-read indexing (identical swizzle to rounds 2-3 — verified)
  const int fr = lane & 15;
  const int kq = lane >> 4;
  const int sx = (fr & 7) << 4;
  const int cS0 = (kq * 16) ^ sx;
  const int cS1 = (64 + kq * 16) ^ sx;
  // staging indexing (identical to rounds 2-3)
  const int lr  = lane >> 3;
  const int sc8 = ((lane & 7) ^ (lr & 7)) << 3;

  const _Float16* Asrc = A + (size_t)(bm + wv * 16 + lr) * lda + sc8;
  const _Float16* Bsrc = B + (size_t)(bn + wv * 16 + lr) * ldb + sc8;
  const size_t lda8 = (size_t)lda * 8,  ldaH = (size_t)lda * 128;
  const size_t ldb8 = (size_t)ldb * 8,  ldbH = (size_t)ldb * 128;
  const int wvd = wv * 2048;

  f32x4 acc[8][4];
  const f32x4 zf = {0.f, 0.f, 0.f, 0.f};
#pragma unroll
  for (int mi = 0; mi < 8; ++mi)
#pragma unroll
    for (int ni = 0; ni < 4; ++ni) acc[mi][ni] = zf;

  half8 af0[4][2], af1[4][2], b0[2][2], b1[2][2];

  const int NT = K >> 6;      // 32 or 64 (even)
  const int NI = NT >> 1;

  // prologue: stage tile 0 into buf0, fence
  STAGE8(0, 0);
  VMC(0);
  SBARF();

  for (int it = 0; it < NI; ++it) {
    const size_t kA = (size_t)(2 * it + 1) * 64;   // staged during even tile
    const size_t kB = (size_t)(2 * it + 2) * 64;   // staged during odd tile
    const bool sB = (2 * it + 2) < NT;
    TILEB(0, kA, 1);
    TILEB(1, kB, sB);
  }

  // epilogue. C/D frag: col = lane&15, rows = (lane>>4)*4 + j
#pragma unroll
  for (int mi = 0; mi < 8; ++mi) {
#pragma unroll
    for (int ni = 0; ni < 4; ++ni) {
      const int col  = bn + wc * 64 + ni * 16 + fr;
      const int row0 = bm + wr * 128 + mi * 16 + kq * 4;
      const f32x4 a = acc[mi][ni];
      if constexpr (MODE == 0) {
        float* O = (float*)out + (size_t)blockIdx.z * sO;
#pragma unroll
        for (int j = 0; j < 4; ++j) O[(size_t)(row0 + j) * ldo + col] = a[j];
      } else if constexpr (MODE == 1) {
        _Float16* O = (_Float16*)out;
        const float bb = bias[col];
#pragma unroll
        for (int j = 0; j < 4; ++j)
          O[(size_t)(row0 + j) * ldo + col] = (_Float16)(a[j] + bb);
      } else {
        _Float16* O = (_Float16*)out;
        const float bb = bias[col];
        half4 h;
#pragma unroll
        for (int j = 0; j < 4; ++j) h[j] = (_Float16)(a[j] + bb);
        *(half4*)(O + (size_t)col * ldo + row0) = h;
      }
    }
  }
}

__device__ __forceinline__ float wave_max_f(float v) {
#pragma unroll
  for (int o = 32; o; o >>= 1) v = fmaxf(v, __shfl_xor(v, o));
  return v;
}
__device__ __forceinline__ float wave_sum_f(float v) {
#pragma unroll
  for (int o = 32; o; o >>= 1) v += __shfl_xor(v, o);
  return v;
}

// one 256-thread block per row of 4096 fp32 scores -> fp16 probabilities
__global__ __launch_bounds__(256) void softmax_rows(
    const float* __restrict__ S, _Float16* __restrict__ P)
{
  __shared__ float rmax[4], rsum[4];
  const int tid = threadIdx.x;
  const float* s = S + (size_t)blockIdx.x * 4096;
  _Float16*    p = P + (size_t)blockIdx.x * 4096;

  f32x4 v[4];
  float m = -3.0e38f;
#pragma unroll
  for (int i = 0; i < 4; ++i) {
    v[i] = ((const f32x4*)s)[i * 256 + tid];
#pragma unroll
    for (int j = 0; j < 4; ++j) m = fmaxf(m, v[i][j]);
  }
  m = wave_max_f(m);
  if ((tid & 63) == 0) rmax[tid >> 6] = m;
  __syncthreads();
  m = fmaxf(fmaxf(rmax[0], rmax[1]), fmaxf(rmax[2], rmax[3]));

  float e[16];
  float sum = 0.f;
#pragma unroll
  for (int i = 0; i < 4; ++i)
#pragma unroll
    for (int j = 0; j < 4; ++j) {
      const float t = __expf(v[i][j] - m);
      e[i * 4 + j] = t;
      sum += t;
    }
  sum = wave_sum_f(sum);
  if ((tid & 63) == 0) rsum[tid >> 6] = sum;
  __syncthreads();
  sum = rsum[0] + rsum[1] + rsum[2] + rsum[3];
  const float inv = 1.0f / sum;

#pragma unroll
  for (int i = 0; i < 4; ++i) {
    half4 h;
#pragma unroll
    for (int j = 0; j < 4; ++j) h[j] = (_Float16)(e[i * 4 + j] * inv);
    ((half4*)p)[i * 256 + tid] = h;
  }
}

__global__ __launch_bounds__(256) void cvt_f32_f16(
    const float* __restrict__ in, _Float16* __restrict__ out, int n4)
{
  const int stride = gridDim.x * 256;
  for (int idx = blockIdx.x * 256 + threadIdx.x; idx < n4; idx += stride) {
    const f32x4 x = ((const f32x4*)in)[idx];
    half4 h;
#pragma unroll
    for (int j = 0; j < 4; ++j) h[j] = (_Float16)x[j];
    ((half4*)out)[idx] = h;
  }
}

extern "C" void kernel_launch(void* const* d_in, const int* in_sizes, int n_in,
                              void* d_out, int out_size, void* d_ws, size_t ws_size,
                              hipStream_t stream)
{
  const float* X  = (const float*)d_in[0];
  const float* Wq = (const float*)d_in[1];
  const float* bq = (const float*)d_in[2];
  const float* Wk = (const float*)d_in[3];
  const float* bk = (const float*)d_in[4];
  const float* Wv = (const float*)d_in[5];
  const float* bv = (const float*)d_in[6];
  float* out = (float*)d_out;

  const size_t NX = (size_t)2 * 4096 * 2048;  // 16,777,216
  const size_t NW = (size_t)2048 * 2048;      //  4,194,304
  const size_t NS = (size_t)2 * 4096 * 4096;  // 33,554,432

  // Workspace layout (lifetime-aliased, total ~235 MB)
  char* w = (char*)d_ws;
  float*    Ssc = (float*)w;
  _Float16* Xh  = (_Float16*)w;
  _Float16* Wqh = (_Float16*)(w + NX * 2);
  _Float16* Wkh = (_Float16*)(w + NX * 2 + NW * 2);
  _Float16* Wvh = (_Float16*)(w + NX * 2 + 2 * NW * 2);
  _Float16* Q   = (_Float16*)(w + NS * 4);
  _Float16* Kp  = (_Float16*)(w + NS * 4 + NX * 2);
  _Float16* P   = (_Float16*)(w + NS * 4);            // aliases Q+Kp
  _Float16* Vt  = (_Float16*)(w + NS * 4 + 2 * NX * 2);

  // 1) fp32 -> fp16 conversions
  cvt_f32_f16<<<2048, 256, 0, stream>>>(X,  Xh,  (int)(NX / 4));
  cvt_f32_f16<<<512,  256, 0, stream>>>(Wq, Wqh, (int)(NW / 4));
  cvt_f32_f16<<<512,  256, 0, stream>>>(Wk, Wkh, (int)(NW / 4));
  cvt_f32_f16<<<512,  256, 0, stream>>>(Wv, Wvh, (int)(NW / 4));

  const dim3 blk(512);
  // 2) projections: [8192,2048] = Xh @ W^T + b
  gemm256<1><<<dim3(32, 8, 1), blk, 0, stream>>>(Xh, 2048, Wqh, 2048, bq,
                                                 Q, 2048, 2048, 0, 0, 0);
  gemm256<1><<<dim3(32, 8, 1), blk, 0, stream>>>(Xh, 2048, Wkh, 2048, bk,
                                                 Kp, 2048, 2048, 0, 0, 0);
  gemm256<2><<<dim3(32, 8, 1), blk, 0, stream>>>(Xh, 2048, Wvh, 2048, bv,
                                                 Vt, 8192, 2048, 0, 0, 0);
  // 3) scores: per batch, S = Q K^T (fp32)
  gemm256<0><<<dim3(16, 16, 2), blk, 0, stream>>>(
      Q, 2048, Kp, 2048, nullptr, Ssc, 4096, 2048,
      (size_t)4096 * 2048, (size_t)4096 * 2048, (size_t)4096 * 4096);
  // 4) row softmax -> fp16 probs
  softmax_rows<<<8192, 256, 0, stream>>>(Ssc, P);
  // 5) out: per batch, [4096,2048] = P @ Vt^T
  gemm256<0><<<dim3(16, 8, 2), blk, 0, stream>>>(
      P, 4096, Vt, 8192, nullptr, out, 2048, 4096,
      (size_t)4096 * 4096, (size_t)4096, (size_t)4096 * 2048);
}